// Round 15
// baseline (301.141 us; speedup 1.0000x reference)
//
#include <hip/hip_runtime.h>
#include <hip/hip_bf16.h>

#define NG 64       // NUM_GROUPS
#define TOPK 8
#define BM 128      // BLOCK_M
#define NSLOT 65536 // NUM_TOKENS * TOPK
#define HID 4096
#define NTOK 8192
#define NSEG 128    // segments of 512 ids each (one wave per segment)
#define NWAVE 128

typedef unsigned int v4u __attribute__((ext_vector_type(4)));
typedef unsigned int v2u __attribute__((ext_vector_type(2)));

// ws ints:
// [0..63]     out_start[e]
// [64..127]   cnt[e]
// [128..191]  padded[e]
// [192..255]  lastslot[e]
// [256]       total
// [257]       ticket (memset to 0 on stream each call -> aligned barrier base)
// [320..8511]   segcnt[e*128+s]
// [8512..16703] lastm[e*128+s]
// rank u16 at ws + 16704 ints (131072 B) -> scratch ~196 KB

// K1: fused hist + device barrier + scan + rank. 32 blocks x 4 waves;
// wave w of block b owns segment s = 4b+w (512 ids, kept in registers).
__global__ __launch_bounds__(256) void prep_k(const int* __restrict__ ids,
                                              int* __restrict__ ws,
                                              unsigned short* __restrict__ rank) {
    int lane = threadIdx.x & 63;
    int s = blockIdx.x * 4 + (threadIdx.x >> 6);
    int segbase = s * 512;
    unsigned long long below = (1ULL << lane) - 1ULL;

    // Phase A: ballot-count; lane e accumulates count/lastslot of expert e.
    int myid[8];
#pragma unroll
    for (int c = 0; c < 8; c++) myid[c] = ids[segbase + c * 64 + lane] & (NG - 1);
    int cnt = 0, lastm = -1;
#pragma unroll
    for (int c = 0; c < 8; c++) {
        int id = myid[c];
#pragma unroll 8
        for (int x = 0; x < NG; x++) {
            unsigned long long m = __ballot(id == x);
            if (m && lane == x) {
                cnt += (int)__popcll(m);
                lastm = segbase + c * 64 + (63 - __builtin_clzll(m));
            }
        }
    }
    ws[320 + lane * NSEG + s] = cnt;
    ws[8512 + lane * NSEG + s] = lastm;
    __threadfence();  // release this wave's publishes

    // Full barrier across the 128 co-resident waves (32 blocks << 256 CUs).
    // Ticket starts at 0 (memset on stream) => every wave's target is NWAVE.
    int win = 0;
    if (lane == 0) {
        unsigned old = atomicAdd((unsigned*)&ws[257], 1u);
        win = (old == NWAVE - 1) ? 1 : 0;
        while (__hip_atomic_load((unsigned*)&ws[257], __ATOMIC_RELAXED,
                                 __HIP_MEMORY_SCOPE_AGENT) < NWAVE) {}
    }
    win = __shfl(win, 0);   // forces wave reconvergence after lane0's spin
    __threadfence();        // acquire: all waves' publishes visible

    // Phase B (winner wave only): per-expert totals + exclusive scan.
    if (win) {
        int c = 0, last = -1;
        for (int b2 = 0; b2 < NSEG; b2++) {
            c += ws[320 + lane * NSEG + b2];
            int l = ws[8512 + lane * NSEG + b2];
            last = l > last ? l : last;
        }
        int p = (c + BM - 1) / BM * BM;
        ws[64 + lane] = c;
        ws[128 + lane] = p;
        ws[192 + lane] = last;
        int acc = p;  // inclusive shfl scan -> exclusive out_start
        for (int off = 1; off < 64; off <<= 1) {
            int v = __shfl_up(acc, off);
            if (lane >= off) acc += v;
        }
        ws[lane] = acc - p;
        if (lane == 63) ws[256] = acc;  // total
    }

    // Phase C (all waves): stable rank of own segment from registers.
    int base = 0;
    for (int s2 = 0; s2 < s; s2++) base += ws[320 + lane * NSEG + s2];
#pragma unroll
    for (int c = 0; c < 8; c++) {
        int id = myid[c];
        int r = 0;
#pragma unroll 8
        for (int x = 0; x < NG; x++) {
            unsigned long long m = __ballot(id == x);
            if (m) {
                int bx = __shfl(base, x);
                if (id == x) r = bx + __popcll(m & below);
                if (lane == x) base += (int)__popcll(m);
            }
        }
        rank[segbase + c * 64 + lane] = (unsigned short)r;
    }
}

// K2: token-grouped scatter (per-instruction wave-contiguous stores) +
// m_indices + pad rows + inv_perm trailing blocks. Identical to round 13.
__global__ __launch_bounds__(256) void copy_k(const __hip_bfloat16* __restrict__ hs,
                                              const int* __restrict__ ids,
                                              const int* __restrict__ ws,
                                              const unsigned short* __restrict__ rank,
                                              float* __restrict__ out) {
    __shared__ int s_last[NG], s_pad[NG];
    int b = blockIdx.x;
    int total = ws[256];
    int t = threadIdx.x;
    float* m_out = out + (size_t)total * HID;
    if (b < NTOK) {
        const v2u* s2 = (const v2u*)(hs + (size_t)b * HID);  // 1024 x 8B
        v4u a[4];
#pragma unroll
        for (int q = 0; q < 4; q++) {
            v2u w = s2[t + 256 * q];
            a[q].x = w.x << 16; a[q].y = w.x & 0xFFFF0000u;
            a[q].z = w.y << 16; a[q].w = w.y & 0xFFFF0000u;
        }
        int slot0 = b * TOPK;
#pragma unroll
        for (int k = 0; k < TOPK; k++) {
            int e = ids[slot0 + k] & (NG - 1);
            int dst = ws[e] + (int)rank[slot0 + k];
            if (dst < 0 || dst >= total) continue;
            v4u* d = (v4u*)(out + (size_t)dst * HID);  // 1024 x 16B
#pragma unroll
            for (int q = 0; q < 4; q++) d[t + 256 * q] = a[q];
            if (t == 0) m_out[dst] = (float)e;
        }
    } else if (b < NTOK + NG * BM) {
        int q0 = b - NTOK;
        int e = q0 >> 7;
        int j = q0 & 127;
        int c = ws[64 + e], p = ws[128 + e];
        if (c + j >= p) return;
        int srcslot = ws[192 + e];
        int dst = ws[e] + c + j;
        if (dst < 0 || dst >= total) return;
        int src = srcslot >> 3;
        if (src < 0 || src >= NTOK) return;
        if (t == 0) m_out[dst] = (float)e;
        const v2u* s2 = (const v2u*)(hs + (size_t)src * HID);
        v4u* d = (v4u*)(out + (size_t)dst * HID);
#pragma unroll
        for (int q = 0; q < 4; q++) {
            v2u w = s2[t + 256 * q];
            v4u a = {w.x << 16, w.x & 0xFFFF0000u, w.y << 16, w.y & 0xFFFF0000u};
            d[t + 256 * q] = a;
        }
    } else {
        // inv_perm: inv[v + sum_{f: last_f < v} pad_f] = pos(v); pads follow last slot.
        if (t < NG) {
            s_last[t] = ws[192 + t];
            s_pad[t] = ws[128 + t] - ws[64 + t];
        }
        __syncthreads();
        float* inv_out = out + (size_t)total * (HID + 1);
        int i = (b - NTOK - NG * BM) * 256 + t;
        int e = ids[i] & (NG - 1);
        int pos = ws[e] + (int)rank[i];
        int base = i;
#pragma unroll
        for (int f = 0; f < NG; f++) {
            int l = s_last[f];
            base += (l >= 0 && l < i) ? s_pad[f] : 0;
        }
        if (base < NSLOT) inv_out[base] = (float)pos;
        if (i == s_last[e]) {
            int oc = ws[e] + ws[64 + e];
            int pd = s_pad[e];
            for (int j = 0; j < pd; j++) {
                int idx = base + 1 + j;
                if (idx >= NSLOT) break;
                inv_out[idx] = (float)(oc + j);
            }
        }
    }
}

extern "C" void kernel_launch(void* const* d_in, const int* in_sizes, int n_in,
                              void* d_out, int out_size, void* d_ws, size_t ws_size,
                              hipStream_t stream) {
    const __hip_bfloat16* hs = (const __hip_bfloat16*)d_in[0];
    const int* ids = (const int*)d_in[1];
    float* out = (float*)d_out;  // mixed-dtype tuple => harness packs as float32

    int* ws = (int*)d_ws;
    unsigned short* rank = (unsigned short*)(ws + 16704);

    // Zero the barrier ticket on-stream (graph-capturable, replay-deterministic).
    hipMemsetAsync((void*)(ws + 257), 0, sizeof(int), stream);
    hipLaunchKernelGGL(prep_k, dim3(32), dim3(256), 0, stream, ids, ws, rank);
    hipLaunchKernelGGL(copy_k, dim3(NTOK + NG * BM + NSLOT / 256), dim3(256), 0, stream,
                       hs, ids, ws, rank, out);
}

// Round 16
// 297.591 us; speedup vs baseline: 1.0119x; 1.0119x over previous
//
#include <hip/hip_runtime.h>
#include <hip/hip_bf16.h>

#define NG 64       // NUM_GROUPS
#define TOPK 8
#define BM 128      // BLOCK_M
#define NSLOT 65536 // NUM_TOKENS * TOPK
#define HID 4096
#define NTOK 8192
#define NSEG 64     // segments of 1024 ids each

typedef unsigned int v4u __attribute__((ext_vector_type(4)));
typedef unsigned int v2u __attribute__((ext_vector_type(2)));

// ws ints:
// [0..63]     out_start[e]
// [64..127]   cnt[e]
// [128..191]  padded[e]
// [192..255]  lastslot[e]
// [256]       total
// [257]       ticket (never reset; winner = (old & 63)==63)
// [320..4415] segcnt[e*64+s]
// [4416..8511] lastm[e*64+s]
// rank u16 at ws + 8704 ints (131072 B) -> scratch ~166 KB

// K1: per-segment hist, then last-arriving block performs the expert scan.
__global__ __launch_bounds__(256) void hist_scan_k(const int* __restrict__ ids,
                                                   int* __restrict__ ws) {
    __shared__ int h[NG], lm[NG];
    __shared__ int winner;
    int t = threadIdx.x, s = blockIdx.x;
    if (t < NG) { h[t] = 0; lm[t] = -1; }
    __syncthreads();
    int base = s * 1024;
    for (int i = t; i < 1024; i += 256) {
        int e = ids[base + i] & (NG - 1);
        atomicAdd(&h[e], 1);
        atomicMax(&lm[e], base + i);
    }
    __syncthreads();
    if (t < NG) {
        ws[320 + t * 64 + s] = h[t];
        ws[4416 + t * 64 + s] = lm[t];
    }
    __threadfence();
    __syncthreads();
    if (t == 0) {
        unsigned old = atomicAdd((unsigned*)&ws[257], 1u);
        winner = ((old & 63u) == 63u) ? 1 : 0;
    }
    __syncthreads();
    if (!winner) return;
    __threadfence();
    if (t < NG) {
        int e = t, c = 0, last = -1;
        for (int b = 0; b < NSEG; b++) {
            c += ws[320 + e * 64 + b];
            int l = ws[4416 + e * 64 + b];
            last = l > last ? l : last;
        }
        ws[64 + e] = c;
        ws[128 + e] = (c + BM - 1) / BM * BM;
        ws[192 + e] = last;
    }
    __syncthreads();
    if (t == 0) {
        int acc = 0;
        for (int f = 0; f < NG; f++) { ws[f] = acc; acc += ws[128 + f]; }
        ws[256] = acc;  // total
    }
}

// K2: one wave per segment; lane e self-computes its within-expert base
// (prefix of segcnt over earlier segments), then ballot-ranks the segment.
__global__ __launch_bounds__(64) void rank_k(const int* __restrict__ ids,
                                             const int* __restrict__ ws,
                                             unsigned short* __restrict__ rank) {
    int s = blockIdx.x;
    int lane = threadIdx.x;
    int base = 0;
    for (int s2 = 0; s2 < s; s2++) base += ws[320 + lane * 64 + s2];
    int segbase = s * 1024;
    unsigned long long below = (1ULL << lane) - 1ULL;
    for (int c0 = 0; c0 < 1024; c0 += 64) {
        int e = ids[segbase + c0 + lane] & (NG - 1);
        int r = 0;
#pragma unroll 8
        for (int x = 0; x < NG; x++) {
            unsigned long long m = __ballot(e == x);
            if (m) {
                int bx = __shfl(base, x);
                if (e == x) r = bx + __popcll(m & below);
                if (lane == x) base += (int)__popcll(m);
            }
        }
        rank[segbase + c0 + lane] = (unsigned short)r;
    }
}

// K3: token-grouped scatter (wave-contiguous stores). m_indices is NOT written
// here (the t==0 scattered 4B stores caused 16-way cross-XCD line sharing);
// instead trailing blocks fill m with full-wave contiguous stores.
// Ranges: [0,NTOK) tokens | [NTOK,+NG*BM) pads | +NSLOT/256 inv | +288 m-fill.
__global__ __launch_bounds__(256) void copy_k(const __hip_bfloat16* __restrict__ hs,
                                              const int* __restrict__ ids,
                                              const int* __restrict__ ws,
                                              const unsigned short* __restrict__ rank,
                                              float* __restrict__ out) {
    __shared__ int s_last[NG], s_pad[NG], s_start[NG];
    int b = blockIdx.x;
    int total = ws[256];
    int t = threadIdx.x;
    if (b < NTOK) {
        const v2u* s2 = (const v2u*)(hs + (size_t)b * HID);  // 1024 x 8B
        v4u a[4];
#pragma unroll
        for (int q = 0; q < 4; q++) {
            v2u w = s2[t + 256 * q];
            a[q].x = w.x << 16; a[q].y = w.x & 0xFFFF0000u;
            a[q].z = w.y << 16; a[q].w = w.y & 0xFFFF0000u;
        }
        int slot0 = b * TOPK;
#pragma unroll
        for (int k = 0; k < TOPK; k++) {
            int e = ids[slot0 + k] & (NG - 1);
            int dst = ws[e] + (int)rank[slot0 + k];
            if (dst < 0 || dst >= total) continue;
            v4u* d = (v4u*)(out + (size_t)dst * HID);  // 1024 x 16B
#pragma unroll
            for (int q = 0; q < 4; q++) d[t + 256 * q] = a[q];
        }
    } else if (b < NTOK + NG * BM) {
        int q0 = b - NTOK;
        int e = q0 >> 7;
        int j = q0 & 127;
        int c = ws[64 + e], p = ws[128 + e];
        if (c + j >= p) return;
        int srcslot = ws[192 + e];
        int dst = ws[e] + c + j;
        if (dst < 0 || dst >= total) return;
        int src = srcslot >> 3;
        if (src < 0 || src >= NTOK) return;
        const v2u* s2 = (const v2u*)(hs + (size_t)src * HID);
        v4u* d = (v4u*)(out + (size_t)dst * HID);
#pragma unroll
        for (int q = 0; q < 4; q++) {
            v2u w = s2[t + 256 * q];
            v4u a = {w.x << 16, w.x & 0xFFFF0000u, w.y << 16, w.y & 0xFFFF0000u};
            d[t + 256 * q] = a;
        }
    } else if (b < NTOK + NG * BM + NSLOT / 256) {
        // inv_perm: inv[v + sum_{f: last_f < v} pad_f] = pos(v); pads follow last slot.
        if (t < NG) {
            s_last[t] = ws[192 + t];
            s_pad[t] = ws[128 + t] - ws[64 + t];
        }
        __syncthreads();
        float* inv_out = out + (size_t)total * (HID + 1);
        int i = (b - NTOK - NG * BM) * 256 + t;
        int e = ids[i] & (NG - 1);
        int pos = ws[e] + (int)rank[i];
        int base = i;
#pragma unroll
        for (int f = 0; f < NG; f++) {
            int l = s_last[f];
            base += (l >= 0 && l < i) ? s_pad[f] : 0;
        }
        if (base < NSLOT) inv_out[base] = (float)pos;
        if (i == s_last[e]) {
            int oc = ws[e] + ws[64 + e];
            int pd = s_pad[e];
            for (int j = 0; j < pd; j++) {
                int idx = base + 1 + j;
                if (idx >= NSLOT) break;
                inv_out[idx] = (float)(oc + j);
            }
        }
    } else {
        // m-fill: full-wave contiguous stores; expert via binary search on out_start.
        if (t < NG) s_start[t] = ws[t];
        __syncthreads();
        int r = (b - NTOK - NG * BM - NSLOT / 256) * 256 + t;
        if (r >= total) return;
        int lo = 0, hi = NG - 1;
#pragma unroll
        for (int it = 0; it < 6; it++) {
            int mid = (lo + hi + 1) >> 1;
            if (s_start[mid] <= r) lo = mid; else hi = mid - 1;
        }
        out[(size_t)total * HID + r] = (float)lo;
    }
}

extern "C" void kernel_launch(void* const* d_in, const int* in_sizes, int n_in,
                              void* d_out, int out_size, void* d_ws, size_t ws_size,
                              hipStream_t stream) {
    const __hip_bfloat16* hs = (const __hip_bfloat16*)d_in[0];
    const int* ids = (const int*)d_in[1];
    float* out = (float*)d_out;  // mixed-dtype tuple => harness packs as float32

    int* ws = (int*)d_ws;
    unsigned short* rank = (unsigned short*)(ws + 8704);

    hipLaunchKernelGGL(hist_scan_k, dim3(NSEG), dim3(256), 0, stream, ids, ws);
    hipLaunchKernelGGL(rank_k, dim3(NSEG), dim3(64), 0, stream, ids, ws, rank);
    // +288 trailing m-fill blocks (288*256 = 73728 >= max total 73664)
    hipLaunchKernelGGL(copy_k, dim3(NTOK + NG * BM + NSLOT / 256 + 288), dim3(256), 0,
                       stream, hs, ids, ws, rank, out);
}